// Round 1
// baseline (324.712 us; speedup 1.0000x reference)
//
#include <hip/hip_runtime.h>
#include <cstdint>
#include <cstddef>

#define B_   4
#define C_   512
#define N_   4096
#define C8_  64
#define BN_EPS 1e-5f

typedef __attribute__((ext_vector_type(8))) short short8;
typedef __attribute__((ext_vector_type(8))) unsigned short ushort8;
typedef __attribute__((ext_vector_type(4))) float f32x4;

__device__ __forceinline__ unsigned short f2b(float f) {
  union { float f; unsigned u; } v; v.f = f;
  unsigned u = v.u;
  return (unsigned short)((u + 0x7fffu + ((u >> 16) & 1u)) >> 16);
}
__device__ __forceinline__ float b2f(unsigned short h) {
  union { unsigned u; float f; } v; v.u = ((unsigned)h) << 16;
  return v.f;
}
__device__ __forceinline__ void async16(const void* g, void* l) {
  __builtin_amdgcn_global_load_lds((const __attribute__((address_space(1))) void*)g,
                                   (__attribute__((address_space(3))) void*)l, 16, 0, 0);
}

// ---------------- conversion kernels ----------------

// x [B][C][N] f32 -> xcn bf16 (same layout) + xnc bf16 (transposed [B][N][C])
__global__ __launch_bounds__(256) void convert_x_k(const float* __restrict__ x,
                                                   unsigned short* __restrict__ xcn,
                                                   unsigned short* __restrict__ xnc) {
  __shared__ float tile[64][65];
  int c0 = blockIdx.x * 64, n0 = blockIdx.y * 64, b = blockIdx.z;
  const float* xb = x + ((size_t)b * C_ + c0) * N_ + n0;
  unsigned short* cn = xcn + ((size_t)b * C_ + c0) * N_ + n0;
#pragma unroll
  for (int j = 0; j < 16; ++j) {
    int lin = j * 256 + threadIdx.x;
    int rr = lin >> 6, cc = lin & 63;            // rr=c, cc=n
    float v = xb[(size_t)rr * N_ + cc];
    cn[(size_t)rr * N_ + cc] = f2b(v);
    tile[cc][rr] = v;
  }
  __syncthreads();
  unsigned short* nc = xnc + ((size_t)b * N_ + n0) * C_ + c0;
#pragma unroll
  for (int j = 0; j < 16; ++j) {
    int lin = j * 256 + threadIdx.x;
    int rr = lin >> 6, cc = lin & 63;            // rr=n, cc=c
    nc[(size_t)rr * C_ + cc] = f2b(tile[rr][cc]);
  }
}

// weights -> bf16; wq,wk stacked into wqk [128][512]
__global__ __launch_bounds__(256) void convert_w_k(const float* __restrict__ wq, const float* __restrict__ wk,
                                                   const float* __restrict__ wv, const float* __restrict__ wf,
                                                   unsigned short* __restrict__ wqk,
                                                   unsigned short* __restrict__ wvb,
                                                   unsigned short* __restrict__ wfb) {
  int i = blockIdx.x * 256 + threadIdx.x;        // grid covers 262144
  if (i < 128 * 512) {
    int row = i >> 9, col = i & 511;
    float v = (row < 64) ? wq[row * 512 + col] : wk[(row - 64) * 512 + col];
    wqk[i] = f2b(v);
  }
  wvb[i] = f2b(wv[i]);
  wfb[i] = f2b(wf[i]);
}

// ---------------- generic MFMA GEMM:  C[m,n] = sum_k A[m,k] * B'[n,k] ----------------

enum { EPI_BF16 = 0, EPI_F32 = 1, EPI_EXP = 2, EPI_S = 3 };

template<int EPI, bool SPLITK = false>
__global__ __launch_bounds__(256)
void gemm_bt(const unsigned short* __restrict__ A, size_t lda, size_t sA,
             const unsigned short* __restrict__ Bm, size_t ldb, size_t sB,
             void* __restrict__ Cv, size_t ldc, size_t sCbytes,
             int K,
             const float* __restrict__ invl,
             const unsigned short* __restrict__ caT,
             const unsigned short* __restrict__ xnc,
             const float* __restrict__ gpa_p,
             const float* __restrict__ gca_p,
             int epiB) {
  const int bz = blockIdx.z;
  const int m0 = blockIdx.x * 128, n0 = blockIdx.y * 128;
  char* Cb;
  int bidx;
  if (SPLITK) {
    bidx = bz & 3;
    int ch = bz >> 2;
    A  += (size_t)bidx * sA + (size_t)ch * (size_t)K;
    Bm += (size_t)bidx * sB + (size_t)ch * (size_t)K;
    Cb = (char*)Cv + (size_t)bidx * sCbytes + (size_t)ch * 4u * sCbytes;
  } else {
    bidx = bz;
    A  += (size_t)bz * sA;
    Bm += (size_t)bz * sB;
    Cb = (char*)Cv + (size_t)bz * sCbytes;
  }
  __shared__ unsigned short lsA[128 * 32];
  __shared__ unsigned short lsB[128 * 32];
  const int tid = threadIdx.x, lane = tid & 63, w = tid >> 6;
  const int wm = (w >> 1) * 64, wn = (w & 1) * 64;
  const int fr = lane & 15, fk = (lane >> 4) * 8;
  f32x4 acc[4][4];
#pragma unroll
  for (int i = 0; i < 4; ++i)
#pragma unroll
    for (int j = 0; j < 4; ++j) acc[i][j] = (f32x4){0.f, 0.f, 0.f, 0.f};

  const int i0 = tid, i1 = tid + 256;
  for (int k0 = 0; k0 < K; k0 += 32) {
    async16(A  + (size_t)(m0 + (i0 >> 2)) * lda + k0 + (i0 & 3) * 8, (char*)lsA + i0 * 16);
    async16(A  + (size_t)(m0 + (i1 >> 2)) * lda + k0 + (i1 & 3) * 8, (char*)lsA + i1 * 16);
    async16(Bm + (size_t)(n0 + (i0 >> 2)) * ldb + k0 + (i0 & 3) * 8, (char*)lsB + i0 * 16);
    async16(Bm + (size_t)(n0 + (i1 >> 2)) * ldb + k0 + (i1 & 3) * 8, (char*)lsB + i1 * 16);
    __syncthreads();
    short8 af[4], bfr[4];
#pragma unroll
    for (int mi = 0; mi < 4; ++mi)
      af[mi] = *(const short8*)&lsA[(wm + mi * 16 + fr) * 32 + fk];
#pragma unroll
    for (int ni = 0; ni < 4; ++ni)
      bfr[ni] = *(const short8*)&lsB[(wn + ni * 16 + fr) * 32 + fk];
#pragma unroll
    for (int mi = 0; mi < 4; ++mi)
#pragma unroll
      for (int ni = 0; ni < 4; ++ni)
        acc[mi][ni] = __builtin_amdgcn_mfma_f32_16x16x32_bf16(af[mi], bfr[ni], acc[mi][ni], 0, 0, 0);
    __syncthreads();
  }
  float gpa = 0.f, gca = 0.f;
  if (EPI == EPI_S) { gpa = gpa_p[0]; gca = gca_p[0]; }
  const int gb = bidx + epiB;
#pragma unroll
  for (int mi = 0; mi < 4; ++mi) {
#pragma unroll
    for (int ni = 0; ni < 4; ++ni) {
#pragma unroll
      for (int r = 0; r < 4; ++r) {
        int gr = m0 + wm + mi * 16 + (lane >> 4) * 4 + r;
        int gc = n0 + wn + ni * 16 + fr;
        float v = acc[mi][ni][r];
        if (EPI == EPI_BF16) {
          ((unsigned short*)Cb)[(size_t)gr * ldc + gc] = f2b(v);
        } else if (EPI == EPI_F32) {
          ((float*)Cb)[(size_t)gr * ldc + gc] = v;
        } else if (EPI == EPI_EXP) {
          ((unsigned short*)Cb)[(size_t)gr * ldc + gc] = f2b(expf(v));
        } else {  // EPI_S: sT = gpa*acc*invl[row] + gca*caT + 2*x
          size_t eo = ((size_t)gb * N_ + gr) * C_ + gc;
          float s = gpa * v * invl[(size_t)gb * N_ + gr] + gca * b2f(caT[eo]) + 2.f * b2f(xnc[eo]);
          ((unsigned short*)Cb)[(size_t)gr * ldc + gc] = f2b(s);
        }
      }
    }
  }
}

// ---------------- row sums of P' -> 1/l ----------------
__global__ __launch_bounds__(256) void rowsum_inv_k(const unsigned short* __restrict__ P,
                                                    float* __restrict__ invl) {
  int wid = threadIdx.x >> 6, lane = threadIdx.x & 63;
  size_t row = (size_t)blockIdx.x * 4 + wid;
  const unsigned short* r = P + row * N_;
  float s = 0.f;
#pragma unroll
  for (int i = 0; i < 8; ++i) {
    ushort8 v = *(const ushort8*)&r[(i * 64 + lane) * 8];
#pragma unroll
    for (int j = 0; j < 8; ++j) s += b2f(v[j]);
  }
#pragma unroll
  for (int o = 1; o < 64; o <<= 1) s += __shfl_xor(s, o, 64);
  if (lane == 0) invl[row] = 1.f / s;
}

// ---------------- channel-attention softmax over ce partials ----------------
// cepart: [4 chunks][B][512][512] f32; cattn[c,d] = exp(min_d ce - ce) / sum
__global__ __launch_bounds__(256) void ce_softmax_k(const float* __restrict__ cepart,
                                                    unsigned short* __restrict__ cattn) {
  int wid = threadIdx.x >> 6, lane = threadIdx.x & 63;
  size_t row = (size_t)blockIdx.x * 4 + wid;          // global row in [0, B*512)
  float v[8]; float mn = 3.4e38f;
#pragma unroll
  for (int i = 0; i < 8; ++i) {
    size_t idx = row * C_ + (size_t)(i * 64 + lane);
    float t = cepart[idx] + cepart[idx + 1048576] + cepart[idx + 2097152] + cepart[idx + 3145728];
    v[i] = t; mn = fminf(mn, t);
  }
#pragma unroll
  for (int o = 1; o < 64; o <<= 1) mn = fminf(mn, __shfl_xor(mn, o, 64));
  float s = 0.f, p[8];
#pragma unroll
  for (int i = 0; i < 8; ++i) { p[i] = expf(mn - v[i]); s += p[i]; }
#pragma unroll
  for (int o = 1; o < 64; o <<= 1) s += __shfl_xor(s, o, 64);
  float inv = 1.f / s;
  unsigned short* orow = cattn + row * C_;
#pragma unroll
  for (int i = 0; i < 8; ++i) orow[i * 64 + lane] = f2b(p[i] * inv);
}

// ---------------- BN statistics (two stage, deterministic) ----------------
__global__ __launch_bounds__(256) void bn_part_k(const float* __restrict__ yT,
                                                 float* __restrict__ part) {
  int p = blockIdx.x, t = threadIdx.x;
  const float* base = yT + (size_t)p * 256 * C_;
  float s0 = 0, q0 = 0, s1 = 0, q1 = 0;
  for (int r = 0; r < 256; ++r) {
    float a = base[(size_t)r * C_ + t];
    float b = base[(size_t)r * C_ + t + 256];
    s0 += a; q0 += a * a; s1 += b; q1 += b * b;
  }
  float* pp = part + (size_t)p * 1024;
  pp[t] = s0; pp[t + 256] = s1; pp[t + 512] = q0; pp[t + 768] = q1;
}

__global__ __launch_bounds__(256) void bn_final_k(const float* __restrict__ part,
                                                  const float* __restrict__ bns,
                                                  const float* __restrict__ bnb,
                                                  float* __restrict__ ab) {
  int t = threadIdx.x;
#pragma unroll
  for (int cc = 0; cc < 2; ++cc) {
    int c = t + cc * 256;
    float s = 0, q = 0;
    for (int p = 0; p < 64; ++p) { s += part[p * 1024 + c]; q += part[p * 1024 + 512 + c]; }
    float mean = s * (1.f / 16384.f);
    float var  = q * (1.f / 16384.f) - mean * mean;
    float istd = rsqrtf(var + BN_EPS);
    float a = bns[c] * istd;
    float b = bnb[c] - mean * a;
    ab[c * 2] = a; ab[c * 2 + 1] = b;
  }
}

// out[b][o][n] = relu(yT[b][n][o]*a_o + b_o)   (transpose via LDS)
__global__ __launch_bounds__(256) void bn_apply_k(const float* __restrict__ yT,
                                                  const float* __restrict__ ab,
                                                  float* __restrict__ out) {
  __shared__ float tile[64][65];
  int n0 = blockIdx.x * 64, o0 = blockIdx.y * 64, b = blockIdx.z;
  const float* yb = yT + ((size_t)b * N_ + n0) * C_ + o0;
#pragma unroll
  for (int j = 0; j < 16; ++j) {
    int lin = j * 256 + threadIdx.x;
    int rr = lin >> 6, cc = lin & 63;            // rr=n, cc=o
    float v = yb[(size_t)rr * C_ + cc];
    float a = ab[(o0 + cc) * 2], bb = ab[(o0 + cc) * 2 + 1];
    tile[cc][rr] = fmaxf(v * a + bb, 0.f);
  }
  __syncthreads();
  float* ob = out + ((size_t)b * C_ + o0) * N_ + n0;
#pragma unroll
  for (int j = 0; j < 16; ++j) {
    int lin = j * 256 + threadIdx.x;
    int rr = lin >> 6, cc = lin & 63;            // rr=o, cc=n
    ob[(size_t)rr * N_ + cc] = tile[rr][cc];
  }
}

// ---------------- host launch ----------------

extern "C" void kernel_launch(void* const* d_in, const int* in_sizes, int n_in,
                              void* d_out, int out_size, void* d_ws, size_t ws_size,
                              hipStream_t stream) {
  (void)in_sizes; (void)n_in; (void)out_size;
  const float* x   = (const float*)d_in[0];
  const float* wq  = (const float*)d_in[1];
  const float* wk  = (const float*)d_in[2];
  const float* wv  = (const float*)d_in[3];
  const float* wf  = (const float*)d_in[4];
  const float* gpa = (const float*)d_in[5];
  const float* gca = (const float*)d_in[6];
  const float* bns = (const float*)d_in[7];
  const float* bnb = (const float*)d_in[8];
  float* out = (float*)d_out;

  char* ws = (char*)d_ws;
  size_t off = 0;
  auto carve = [&](size_t bytes) -> char* {
    off = (off + 255) & ~(size_t)255;
    char* p = ws + off; off += bytes; return p;
  };

  unsigned short* xcn   = (unsigned short*)carve((size_t)B_ * C_ * N_ * 2);  // reused as sT
  unsigned short* xnc   = (unsigned short*)carve((size_t)B_ * C_ * N_ * 2);
  unsigned short* wqkb  = (unsigned short*)carve(128 * 512 * 2);
  unsigned short* wvb   = (unsigned short*)carve(512 * 512 * 2);
  unsigned short* wfb   = (unsigned short*)carve(512 * 512 * 2);
  unsigned short* qkT   = (unsigned short*)carve((size_t)B_ * N_ * 128 * 2);
  unsigned short* vmat  = (unsigned short*)carve((size_t)B_ * C_ * N_ * 2);
  float*          invl  = (float*)carve((size_t)B_ * N_ * 4);
  float*          cepart= (float*)carve((size_t)4 * B_ * 512 * 512 * 4);
  unsigned short* cattn = (unsigned short*)carve((size_t)B_ * 512 * 512 * 2);
  unsigned short* caT   = (unsigned short*)carve((size_t)B_ * N_ * C_ * 2);
  float*          bnpart= (float*)carve((size_t)64 * 1024 * 4);
  float*          abv   = (float*)carve(512 * 2 * 4);

  const size_t pFull = (size_t)B_ * N_ * N_ * 2;   // 134 MB
  const size_t pOne  = (size_t)N_ * N_ * 2;        // 33.5 MB (>= yT bytes)
  bool full = (ws_size >= off + pFull + 512);
  unsigned short* Pp = (unsigned short*)carve(full ? pFull : pOne);
  float* yT = (float*)Pp;                           // overlay: yT used only after P'
  unsigned short* sT = xcn;                         // overlay: xcn dead after ce GEMM

  // 1) conversions
  convert_x_k<<<dim3(C_ / 64, N_ / 64, B_), 256, 0, stream>>>(x, xcn, xnc);
  convert_w_k<<<dim3(1024), 256, 0, stream>>>(wq, wk, wv, wf, wqkb, wvb, wfb);

  // 2) qkT[n][0:128] = xnc @ wqk^T
  gemm_bt<EPI_BF16><<<dim3(32, 1, 4), 256, 0, stream>>>(
      xnc, 512, (size_t)N_ * C_, wqkb, 512, 0,
      qkT, 128, (size_t)N_ * 128 * 2, 512, nullptr, nullptr, nullptr, nullptr, nullptr, 0);

  // 3) v[c][m] = wv @ x  (B' = xnc)
  gemm_bt<EPI_BF16><<<dim3(4, 32, 4), 256, 0, stream>>>(
      wvb, 512, 0, xnc, 512, (size_t)N_ * C_,
      vmat, N_, (size_t)C_ * N_ * 2, 512, nullptr, nullptr, nullptr, nullptr, nullptr, 0);

  // 4) ce partials = X X^T (split-K x4: z = chunk*4 + b)
  gemm_bt<EPI_F32, true><<<dim3(4, 4, 16), 256, 0, stream>>>(
      xcn, N_, (size_t)C_ * N_, xcn, N_, (size_t)C_ * N_,
      cepart, 512, (size_t)512 * 512 * 4, 1024, nullptr, nullptr, nullptr, nullptr, nullptr, 0);

  // 5) channel softmax -> cattn bf16
  ce_softmax_k<<<dim3(B_ * 512 / 4), 256, 0, stream>>>(cepart, cattn);

  // 6) caT[n][c] = xnc @ cattn^T
  gemm_bt<EPI_BF16><<<dim3(32, 4, 4), 256, 0, stream>>>(
      xnc, 512, (size_t)N_ * C_, cattn, 512, (size_t)512 * 512,
      caT, 512, (size_t)N_ * C_ * 2, 512, nullptr, nullptr, nullptr, nullptr, nullptr, 0);

  if (full) {
    // 7) P'[n][m] = exp(q^T k)
    gemm_bt<EPI_EXP><<<dim3(32, 32, 4), 256, 0, stream>>>(
        qkT, 128, (size_t)N_ * 128, qkT + 64, 128, (size_t)N_ * 128,
        Pp, N_, (size_t)N_ * N_ * 2, 64, nullptr, nullptr, nullptr, nullptr, nullptr, 0);
    // 8) 1/rowsum
    rowsum_inv_k<<<dim3(B_ * N_ / 4), 256, 0, stream>>>(Pp, invl);
    // 9) sT = bf16(gpa*(P' v^T)*invl + gca*caT + 2x)
    gemm_bt<EPI_S><<<dim3(32, 4, 4), 256, 0, stream>>>(
        Pp, N_, (size_t)N_ * N_, vmat, N_, (size_t)C_ * N_,
        sT, 512, (size_t)N_ * C_ * 2, N_, invl, caT, xnc, gpa, gca, 0);
  } else {
    for (int b = 0; b < B_; ++b) {
      gemm_bt<EPI_EXP><<<dim3(32, 32, 1), 256, 0, stream>>>(
          qkT + (size_t)b * N_ * 128, 128, 0, qkT + (size_t)b * N_ * 128 + 64, 128, 0,
          Pp, N_, 0, 64, nullptr, nullptr, nullptr, nullptr, nullptr, 0);
      rowsum_inv_k<<<dim3(N_ / 4), 256, 0, stream>>>(Pp, invl + (size_t)b * N_);
      gemm_bt<EPI_S><<<dim3(32, 4, 1), 256, 0, stream>>>(
          Pp, N_, 0, vmat + (size_t)b * C_ * N_, N_, 0,
          (char*)sT + (size_t)b * N_ * C_ * 2, 512, 0, N_, invl, caT, xnc, gpa, gca, b);
    }
  }

  // 10) yT[n][o] = sT @ wfuse^T (fp32)
  gemm_bt<EPI_F32><<<dim3(32, 4, 4), 256, 0, stream>>>(
      sT, 512, (size_t)N_ * C_, wfb, 512, 0,
      yT, 512, (size_t)N_ * C_ * 4, 512, nullptr, nullptr, nullptr, nullptr, nullptr, 0);

  // 11) BN stats + apply + transpose + relu
  bn_part_k<<<dim3(64), 256, 0, stream>>>(yT, bnpart);
  bn_final_k<<<dim3(1), 256, 0, stream>>>(bnpart, bns, bnb, abv);
  bn_apply_k<<<dim3(N_ / 64, C_ / 64, B_), 256, 0, stream>>>(yT, abv, out);
}

// Round 3
// 304.390 us; speedup vs baseline: 1.0668x; 1.0668x over previous
//
#include <hip/hip_runtime.h>
#include <cstdint>
#include <cstddef>

#define B_   4
#define C_   512
#define N_   4096
#define BN_EPS 1e-5f

typedef __attribute__((ext_vector_type(8))) short short8;
typedef __attribute__((ext_vector_type(8))) unsigned short ushort8;
typedef __attribute__((ext_vector_type(4))) unsigned short us4_t;
typedef __attribute__((ext_vector_type(4))) float f32x4;

__device__ __forceinline__ unsigned short f2b(float f) {
  union { float f; unsigned u; } v; v.f = f;
  unsigned u = v.u;
  return (unsigned short)((u + 0x7fffu + ((u >> 16) & 1u)) >> 16);
}
__device__ __forceinline__ float b2f(unsigned short h) {
  union { unsigned u; float f; } v; v.u = ((unsigned)h) << 16;
  return v.f;
}
__device__ __forceinline__ void async16(const void* g, void* l) {
  __builtin_amdgcn_global_load_lds((const __attribute__((address_space(1))) void*)g,
                                   (__attribute__((address_space(3))) void*)l, 16, 0, 0);
}

// ---------------- conversion kernels ----------------

__global__ __launch_bounds__(256) void convert_x_k(const float* __restrict__ x,
                                                   unsigned short* __restrict__ xcn,
                                                   unsigned short* __restrict__ xnc) {
  __shared__ float tile[64][65];
  int c0 = blockIdx.x * 64, n0 = blockIdx.y * 64, b = blockIdx.z;
  const float* xb = x + ((size_t)b * C_ + c0) * N_ + n0;
  unsigned short* cn = xcn + ((size_t)b * C_ + c0) * N_ + n0;
#pragma unroll
  for (int j = 0; j < 16; ++j) {
    int lin = j * 256 + threadIdx.x;
    int rr = lin >> 6, cc = lin & 63;
    float v = xb[(size_t)rr * N_ + cc];
    cn[(size_t)rr * N_ + cc] = f2b(v);
    tile[cc][rr] = v;
  }
  __syncthreads();
  unsigned short* nc = xnc + ((size_t)b * N_ + n0) * C_ + c0;
#pragma unroll
  for (int j = 0; j < 16; ++j) {
    int lin = j * 256 + threadIdx.x;
    int rr = lin >> 6, cc = lin & 63;
    nc[(size_t)rr * C_ + cc] = f2b(tile[rr][cc]);
  }
}

__global__ __launch_bounds__(256) void convert_w_k(const float* __restrict__ wq, const float* __restrict__ wk,
                                                   const float* __restrict__ wv, const float* __restrict__ wf,
                                                   unsigned short* __restrict__ wqk,
                                                   unsigned short* __restrict__ wvb,
                                                   unsigned short* __restrict__ wfb) {
  int i = blockIdx.x * 256 + threadIdx.x;
  if (i < 128 * 512) {
    int row = i >> 9, col = i & 511;
    float v = (row < 64) ? wq[row * 512 + col] : wk[(row - 64) * 512 + col];
    wqk[i] = f2b(v);
  }
  wvb[i] = f2b(wv[i]);
  wfb[i] = f2b(wf[i]);
}

// ---------------- generic MFMA GEMM:  C[m,n] = sum_k A[m,k] * B'[n,k] ----------------

enum { EPI_BF16 = 0, EPI_F32 = 1 };

template<int EPI, bool SPLITK = false>
__global__ __launch_bounds__(256)
void gemm_bt(const unsigned short* __restrict__ A, size_t lda, size_t sA,
             const unsigned short* __restrict__ Bm, size_t ldb, size_t sB,
             void* __restrict__ Cv, size_t ldc, size_t sCbytes, int K) {
  const int bz = blockIdx.z;
  const int m0 = blockIdx.x * 128, n0 = blockIdx.y * 128;
  char* Cb;
  if (SPLITK) {
    int bidx = bz & 3, ch = bz >> 2;
    A  += (size_t)bidx * sA + (size_t)ch * (size_t)K;
    Bm += (size_t)bidx * sB + (size_t)ch * (size_t)K;
    Cb = (char*)Cv + (size_t)bidx * sCbytes + (size_t)ch * 4u * sCbytes;
  } else {
    A  += (size_t)bz * sA;
    Bm += (size_t)bz * sB;
    Cb = (char*)Cv + (size_t)bz * sCbytes;
  }
  __shared__ unsigned short lsA[128 * 32];
  __shared__ unsigned short lsB[128 * 32];
  const int tid = threadIdx.x, lane = tid & 63, w = tid >> 6;
  const int wm = (w >> 1) * 64, wn = (w & 1) * 64;
  const int fr = lane & 15, fk = (lane >> 4) * 8;
  f32x4 acc[4][4];
#pragma unroll
  for (int i = 0; i < 4; ++i)
#pragma unroll
    for (int j = 0; j < 4; ++j) acc[i][j] = (f32x4){0.f, 0.f, 0.f, 0.f};

  const int i0 = tid, i1 = tid + 256;
  for (int k0 = 0; k0 < K; k0 += 32) {
    async16(A  + (size_t)(m0 + (i0 >> 2)) * lda + k0 + (i0 & 3) * 8, (char*)lsA + i0 * 16);
    async16(A  + (size_t)(m0 + (i1 >> 2)) * lda + k0 + (i1 & 3) * 8, (char*)lsA + i1 * 16);
    async16(Bm + (size_t)(n0 + (i0 >> 2)) * ldb + k0 + (i0 & 3) * 8, (char*)lsB + i0 * 16);
    async16(Bm + (size_t)(n0 + (i1 >> 2)) * ldb + k0 + (i1 & 3) * 8, (char*)lsB + i1 * 16);
    __syncthreads();
    short8 af[4], bfr[4];
#pragma unroll
    for (int mi = 0; mi < 4; ++mi)
      af[mi] = *(const short8*)&lsA[(wm + mi * 16 + fr) * 32 + fk];
#pragma unroll
    for (int ni = 0; ni < 4; ++ni)
      bfr[ni] = *(const short8*)&lsB[(wn + ni * 16 + fr) * 32 + fk];
#pragma unroll
    for (int mi = 0; mi < 4; ++mi)
#pragma unroll
      for (int ni = 0; ni < 4; ++ni)
        acc[mi][ni] = __builtin_amdgcn_mfma_f32_16x16x32_bf16(af[mi], bfr[ni], acc[mi][ni], 0, 0, 0);
    __syncthreads();
  }
#pragma unroll
  for (int mi = 0; mi < 4; ++mi)
#pragma unroll
    for (int ni = 0; ni < 4; ++ni)
#pragma unroll
      for (int r = 0; r < 4; ++r) {
        int gr = m0 + wm + mi * 16 + (lane >> 4) * 4 + r;
        int gc = n0 + wn + ni * 16 + fr;
        float v = acc[mi][ni][r];
        if (EPI == EPI_BF16) ((unsigned short*)Cb)[(size_t)gr * ldc + gc] = f2b(v);
        else                 ((float*)Cb)[(size_t)gr * ldc + gc] = v;
      }
}

// ---------------- fused position attention ----------------
// per block: 128 Q-rows x 256 out-cols; K-tiles of 128 over m.
// E^T = mfma(K,Q) -> exp -> P (bf16, swizzled LDS) + running rowsum -> P@V^T
// epilogue: sT = bf16(gpa*acc/l + gca*caT + 2x)
#define QR 128
#define CC 256
#define KT 128

__global__ __launch_bounds__(512, 2)
void fused_pa_k(const unsigned short* __restrict__ qkT,   // [B][N][128] (q|k)
                const unsigned short* __restrict__ vmat,  // [B][C][N]
                const unsigned short* __restrict__ caT,   // [B][N][C]
                const unsigned short* __restrict__ xnc,   // [B][N][C]
                const float* __restrict__ gpa_p, const float* __restrict__ gca_p,
                unsigned short* __restrict__ sT) {        // [B][N][C]
  __shared__ unsigned short lsQ[QR * 64];
  __shared__ unsigned short lsK[2][KT * 64];
  __shared__ unsigned short lsV[CC * KT];
  __shared__ unsigned short lsP[QR * KT];
  __shared__ float lsL[8][QR];
  __shared__ float invL[QR];

  const int bid = blockIdx.x;
  const int combo = bid & 7;                 // b*2+chalf -> same XCD shares V-half
  const int b = combo >> 1, chalf = combo & 1;
  const int qt = bid >> 3;
  const int n0 = qt * QR, c0 = chalf * CC;

  const int tid = threadIdx.x, lane = tid & 63, w = tid >> 6;
  const int fr = lane & 15, fq = lane >> 4;  // fragment row / k-quarter
  const int wr = w >> 2, wc = w & 3;         // wave out-tile 64x64

  const unsigned short* qk_b = qkT + (size_t)b * N_ * 128;
  const unsigned short* v_b  = vmat + (size_t)b * C_ * N_;

  f32x4 acc[4][4];
#pragma unroll
  for (int i = 0; i < 4; ++i)
#pragma unroll
    for (int j = 0; j < 4; ++j) acc[i][j] = (f32x4){0.f, 0.f, 0.f, 0.f};
  float lsum[8];
#pragma unroll
  for (int f = 0; f < 8; ++f) lsum[f] = 0.f;

  // stage Q (once) and K[0]
#pragma unroll
  for (int j = 0; j < 2; ++j) {
    int idx = j * 512 + tid;
    int r = idx >> 3, g = idx & 7;
    async16(qk_b + (size_t)(n0 + r) * 128 + ((g ^ (r & 7)) << 3), (char*)lsQ + idx * 16);
  }
#pragma unroll
  for (int j = 0; j < 2; ++j) {
    int idx = j * 512 + tid;
    int r = idx >> 3, g = idx & 7;
    async16(qk_b + (size_t)r * 128 + 64 + ((g ^ (r & 7)) << 3), (char*)lsK[0] + idx * 16);
  }
  __syncthreads();

  for (int it = 0; it < N_ / KT; ++it) {
    const int m0 = it * KT;
    // stage V[it]
#pragma unroll
    for (int j = 0; j < 8; ++j) {
      int idx = j * 512 + tid;
      int c = idx >> 4, g = idx & 15;
      async16(v_b + (size_t)(c0 + c) * N_ + m0 + ((g ^ (c & 7)) << 3), (char*)lsV + idx * 16);
    }
    // stage K[it+1]
    if (it < N_ / KT - 1) {
      unsigned short* dst = lsK[(it + 1) & 1];
#pragma unroll
      for (int j = 0; j < 2; ++j) {
        int idx = j * 512 + tid;
        int r = idx >> 3, g = idx & 7;
        async16(qk_b + (size_t)(m0 + KT + r) * 128 + 64 + ((g ^ (r & 7)) << 3),
                (char*)dst + idx * 16);
      }
    }
    // E^T = K . Q^T over k=64; wave w owns m-slice [w*16, w*16+16)
    const unsigned short* lk = lsK[it & 1];
    const int ms = w * 16;
    short8 afk[2];
#pragma unroll
    for (int kk = 0; kk < 2; ++kk)
      afk[kk] = *(const short8*)&lk[(ms + fr) * 64 + (((kk * 4 + fq) ^ (fr & 7)) << 3)];
#pragma unroll
    for (int f = 0; f < 8; ++f) {
      f32x4 e = (f32x4){0.f, 0.f, 0.f, 0.f};
#pragma unroll
      for (int kk = 0; kk < 2; ++kk) {
        short8 bq = *(const short8*)&lsQ[(f * 16 + fr) * 64 + (((kk * 4 + fq) ^ (fr & 7)) << 3)];
        e = __builtin_amdgcn_mfma_f32_16x16x32_bf16(afk[kk], bq, e, 0, 0, 0);
      }
      float p0 = expf(e[0]), p1 = expf(e[1]), p2 = expf(e[2]), p3 = expf(e[3]);
      float part = p0 + p1 + p2 + p3;
      part += __shfl_xor(part, 16, 64);
      part += __shfl_xor(part, 32, 64);
      lsum[f] += part;
      int n = f * 16 + fr;                     // P row
      int mb = ms + fq * 4;                    // 4 consecutive m
      us4_t pk = { f2b(p0), f2b(p1), f2b(p2), f2b(p3) };
      *(us4_t*)((char*)lsP + n * 256 + ((((mb >> 3) ^ (n & 7)) << 3) + (mb & 7)) * 2) = pk;
    }
    __syncthreads();   // P visible; V (and next K) landed
    // PV: out[n][c] += P[n][m] * V[c][m]
#pragma unroll
    for (int kk4 = 0; kk4 < 4; ++kk4) {
      short8 pa[4], vbf[4];
#pragma unroll
      for (int mi = 0; mi < 4; ++mi) {
        int n = wr * 64 + mi * 16 + fr;
        pa[mi] = *(const short8*)&lsP[n * 128 + (((kk4 * 4 + fq) ^ (n & 7)) << 3)];
      }
#pragma unroll
      for (int ni = 0; ni < 4; ++ni) {
        int c = wc * 64 + ni * 16 + fr;
        vbf[ni] = *(const short8*)&lsV[c * 128 + (((kk4 * 4 + fq) ^ (c & 7)) << 3)];
      }
#pragma unroll
      for (int mi = 0; mi < 4; ++mi)
#pragma unroll
        for (int ni = 0; ni < 4; ++ni)
          acc[mi][ni] = __builtin_amdgcn_mfma_f32_16x16x32_bf16(pa[mi], vbf[ni], acc[mi][ni], 0, 0, 0);
    }
    __syncthreads();   // all reads of lsP/lsV done before next stage/overwrite
  }

  // reduce rowsums across waves -> 1/l
  if (lane < 16) {
#pragma unroll
    for (int f = 0; f < 8; ++f) lsL[w][f * 16 + lane] = lsum[f];
  }
  __syncthreads();
  if (tid < QR) {
    float s = 0.f;
#pragma unroll
    for (int ww = 0; ww < 8; ++ww) s += lsL[ww][tid];
    invL[tid] = 1.f / s;
  }
  __syncthreads();

  const float gpa = gpa_p[0], gca = gca_p[0];
#pragma unroll
  for (int mi = 0; mi < 4; ++mi)
#pragma unroll
    for (int ni = 0; ni < 4; ++ni)
#pragma unroll
      for (int r = 0; r < 4; ++r) {
        int nl = wr * 64 + mi * 16 + fq * 4 + r;
        int gn = n0 + nl;
        int gc = c0 + wc * 64 + ni * 16 + fr;
        size_t eo = ((size_t)b * N_ + gn) * C_ + gc;
        float sv = gpa * acc[mi][ni][r] * invL[nl] + gca * b2f(caT[eo]) + 2.f * b2f(xnc[eo]);
        sT[eo] = f2b(sv);
      }
}

// ---------------- channel-attention softmax over ce partials ----------------
__global__ __launch_bounds__(256) void ce_softmax_k(const float* __restrict__ cepart,
                                                    unsigned short* __restrict__ cattn) {
  int wid = threadIdx.x >> 6, lane = threadIdx.x & 63;
  size_t row = (size_t)blockIdx.x * 4 + wid;
  float v[8]; float mn = 3.4e38f;
#pragma unroll
  for (int i = 0; i < 8; ++i) {
    size_t idx = row * C_ + (size_t)(i * 64 + lane);
    float t = cepart[idx] + cepart[idx + 1048576] + cepart[idx + 2097152] + cepart[idx + 3145728];
    v[i] = t; mn = fminf(mn, t);
  }
#pragma unroll
  for (int o = 1; o < 64; o <<= 1) mn = fminf(mn, __shfl_xor(mn, o, 64));
  float s = 0.f, p[8];
#pragma unroll
  for (int i = 0; i < 8; ++i) { p[i] = expf(mn - v[i]); s += p[i]; }
#pragma unroll
  for (int o = 1; o < 64; o <<= 1) s += __shfl_xor(s, o, 64);
  float inv = 1.f / s;
  unsigned short* orow = cattn + row * C_;
#pragma unroll
  for (int i = 0; i < 8; ++i) orow[i * 64 + lane] = f2b(p[i] * inv);
}

// ---------------- BN statistics (two stage, deterministic) ----------------
__global__ __launch_bounds__(256) void bn_part_k(const float* __restrict__ yT,
                                                 float* __restrict__ part) {
  int p = blockIdx.x, t = threadIdx.x;
  const float* base = yT + (size_t)p * 256 * C_;
  float s0 = 0, q0 = 0, s1 = 0, q1 = 0;
  for (int r = 0; r < 256; ++r) {
    float a = base[(size_t)r * C_ + t];
    float b = base[(size_t)r * C_ + t + 256];
    s0 += a; q0 += a * a; s1 += b; q1 += b * b;
  }
  float* pp = part + (size_t)p * 1024;
  pp[t] = s0; pp[t + 256] = s1; pp[t + 512] = q0; pp[t + 768] = q1;
}

__global__ __launch_bounds__(256) void bn_final_k(const float* __restrict__ part,
                                                  const float* __restrict__ bns,
                                                  const float* __restrict__ bnb,
                                                  float* __restrict__ ab) {
  int t = threadIdx.x;
#pragma unroll
  for (int cc = 0; cc < 2; ++cc) {
    int c = t + cc * 256;
    float s = 0, q = 0;
    for (int p = 0; p < 64; ++p) { s += part[p * 1024 + c]; q += part[p * 1024 + 512 + c]; }
    float mean = s * (1.f / 16384.f);
    float var  = q * (1.f / 16384.f) - mean * mean;
    float istd = rsqrtf(var + BN_EPS);
    float a = bns[c] * istd;
    float b = bnb[c] - mean * a;
    ab[c * 2] = a; ab[c * 2 + 1] = b;
  }
}

__global__ __launch_bounds__(256) void bn_apply_k(const float* __restrict__ yT,
                                                  const float* __restrict__ ab,
                                                  float* __restrict__ out) {
  __shared__ float tile[64][65];
  int n0 = blockIdx.x * 64, o0 = blockIdx.y * 64, b = blockIdx.z;
  const float* yb = yT + ((size_t)b * N_ + n0) * C_ + o0;
#pragma unroll
  for (int j = 0; j < 16; ++j) {
    int lin = j * 256 + threadIdx.x;
    int rr = lin >> 6, cc = lin & 63;
    float v = yb[(size_t)rr * C_ + cc];
    float a = ab[(o0 + cc) * 2], bb = ab[(o0 + cc) * 2 + 1];
    tile[cc][rr] = fmaxf(v * a + bb, 0.f);
  }
  __syncthreads();
  float* ob = out + ((size_t)b * C_ + o0) * N_ + n0;
#pragma unroll
  for (int j = 0; j < 16; ++j) {
    int lin = j * 256 + threadIdx.x;
    int rr = lin >> 6, cc = lin & 63;
    ob[(size_t)rr * N_ + cc] = tile[rr][cc];
  }
}

// ---------------- host launch ----------------

extern "C" void kernel_launch(void* const* d_in, const int* in_sizes, int n_in,
                              void* d_out, int out_size, void* d_ws, size_t ws_size,
                              hipStream_t stream) {
  (void)in_sizes; (void)n_in; (void)out_size; (void)ws_size;
  const float* x   = (const float*)d_in[0];
  const float* wq  = (const float*)d_in[1];
  const float* wk  = (const float*)d_in[2];
  const float* wv  = (const float*)d_in[3];
  const float* wf  = (const float*)d_in[4];
  const float* gpa = (const float*)d_in[5];
  const float* gca = (const float*)d_in[6];
  const float* bns = (const float*)d_in[7];
  const float* bnb = (const float*)d_in[8];
  float* out = (float*)d_out;

  char* ws = (char*)d_ws;
  size_t off = 0;
  auto carve = [&](size_t bytes) -> char* {
    off = (off + 255) & ~(size_t)255;
    char* p = ws + off; off += bytes; return p;
  };

  unsigned short* xcn   = (unsigned short*)carve((size_t)B_ * C_ * N_ * 2);  // reused as sT
  unsigned short* xnc   = (unsigned short*)carve((size_t)B_ * C_ * N_ * 2);
  unsigned short* wqkb  = (unsigned short*)carve(128 * 512 * 2);
  unsigned short* wvb   = (unsigned short*)carve(512 * 512 * 2);
  unsigned short* wfb   = (unsigned short*)carve(512 * 512 * 2);
  unsigned short* qkT   = (unsigned short*)carve((size_t)B_ * N_ * 128 * 2);
  unsigned short* vmat  = (unsigned short*)carve((size_t)B_ * C_ * N_ * 2);
  float*          cepart= (float*)carve((size_t)4 * B_ * 512 * 512 * 4);     // reused as yT
  unsigned short* cattn = (unsigned short*)carve((size_t)B_ * 512 * 512 * 2);
  unsigned short* caT   = (unsigned short*)carve((size_t)B_ * N_ * C_ * 2);
  float*          bnpart= (float*)carve((size_t)64 * 1024 * 4);
  float*          abv   = (float*)carve(512 * 2 * 4);

  float* yT = cepart;                 // overlay: cepart dead after ce_softmax
  unsigned short* sT = xcn;           // overlay: xcn dead after ce GEMM

  // 1) conversions
  convert_x_k<<<dim3(C_ / 64, N_ / 64, B_), 256, 0, stream>>>(x, xcn, xnc);
  convert_w_k<<<dim3(1024), 256, 0, stream>>>(wq, wk, wv, wf, wqkb, wvb, wfb);

  // 2) qkT[n][0:128] = xnc @ wqk^T
  gemm_bt<EPI_BF16><<<dim3(32, 1, 4), 256, 0, stream>>>(
      xnc, 512, (size_t)N_ * C_, wqkb, 512, 0,
      qkT, 128, (size_t)N_ * 128 * 2, 512);

  // 3) v[c][m] = wv @ x
  gemm_bt<EPI_BF16><<<dim3(4, 32, 4), 256, 0, stream>>>(
      wvb, 512, 0, xnc, 512, (size_t)N_ * C_,
      vmat, N_, (size_t)C_ * N_ * 2, 512);

  // 4) ce partials = X X^T (split-K x4)
  gemm_bt<EPI_F32, true><<<dim3(4, 4, 16), 256, 0, stream>>>(
      xcn, N_, (size_t)C_ * N_, xcn, N_, (size_t)C_ * N_,
      cepart, 512, (size_t)512 * 512 * 4, 1024);

  // 5) channel softmax -> cattn bf16
  ce_softmax_k<<<dim3(B_ * 512 / 4), 256, 0, stream>>>(cepart, cattn);

  // 6) caT[n][c] = xnc @ cattn^T
  gemm_bt<EPI_BF16><<<dim3(32, 4, 4), 256, 0, stream>>>(
      xnc, 512, (size_t)N_ * C_, cattn, 512, (size_t)512 * 512,
      caT, 512, (size_t)N_ * C_ * 2, 512);

  // 7) fused position attention + combine epilogue -> sT
  fused_pa_k<<<dim3(256), 512, 0, stream>>>(qkT, vmat, caT, xnc, gpa, gca, sT);

  // 8) yT[n][o] = sT @ wfuse^T (fp32)
  gemm_bt<EPI_F32><<<dim3(32, 4, 4), 256, 0, stream>>>(
      sT, 512, (size_t)N_ * C_, wfb, 512, 0,
      yT, 512, (size_t)N_ * C_ * 4, 512);

  // 9) BN stats + apply + transpose + relu
  bn_part_k<<<dim3(64), 256, 0, stream>>>(yT, bnpart);
  bn_final_k<<<dim3(1), 256, 0, stream>>>(bnpart, bns, bnb, abv);
  bn_apply_k<<<dim3(N_ / 64, C_ / 64, B_), 256, 0, stream>>>(yT, abv, out);
}

// Round 5
// 263.991 us; speedup vs baseline: 1.2300x; 1.1530x over previous
//
#include <hip/hip_runtime.h>
#include <cstdint>
#include <cstddef>

#define B_   4
#define C_   512
#define N_   4096
#define BN_EPS 1e-5f

typedef __attribute__((ext_vector_type(8))) short short8;
typedef __attribute__((ext_vector_type(8))) unsigned short ushort8;
typedef __attribute__((ext_vector_type(4))) unsigned short us4_t;
typedef __attribute__((ext_vector_type(4))) float f32x4;

__device__ __forceinline__ unsigned short f2b(float f) {
  union { float f; unsigned u; } v; v.f = f;
  unsigned u = v.u;
  return (unsigned short)((u + 0x7fffu + ((u >> 16) & 1u)) >> 16);
}
__device__ __forceinline__ float b2f(unsigned short h) {
  union { unsigned u; float f; } v; v.u = ((unsigned)h) << 16;
  return v.f;
}
__device__ __forceinline__ void async16(const void* g, void* l) {
  __builtin_amdgcn_global_load_lds((const __attribute__((address_space(1))) void*)g,
                                   (__attribute__((address_space(3))) void*)l, 16, 0, 0);
}

// ---------------- conversion kernels ----------------

__global__ __launch_bounds__(256) void convert_x_k(const float* __restrict__ x,
                                                   unsigned short* __restrict__ xcn,
                                                   unsigned short* __restrict__ xnc) {
  __shared__ float tile[64][65];
  int c0 = blockIdx.x * 64, n0 = blockIdx.y * 64, b = blockIdx.z;
  const float* xb = x + ((size_t)b * C_ + c0) * N_ + n0;
  unsigned short* cn = xcn + ((size_t)b * C_ + c0) * N_ + n0;
#pragma unroll
  for (int j = 0; j < 16; ++j) {
    int lin = j * 256 + threadIdx.x;
    int rr = lin >> 6, cc = lin & 63;
    float v = xb[(size_t)rr * N_ + cc];
    cn[(size_t)rr * N_ + cc] = f2b(v);
    tile[cc][rr] = v;
  }
  __syncthreads();
  unsigned short* nc = xnc + ((size_t)b * N_ + n0) * C_ + c0;
#pragma unroll
  for (int j = 0; j < 16; ++j) {
    int lin = j * 256 + threadIdx.x;
    int rr = lin >> 6, cc = lin & 63;
    nc[(size_t)rr * C_ + cc] = f2b(tile[rr][cc]);
  }
}

__global__ __launch_bounds__(256) void convert_w_k(const float* __restrict__ wq, const float* __restrict__ wk,
                                                   const float* __restrict__ wv, const float* __restrict__ wf,
                                                   unsigned short* __restrict__ wqk,
                                                   unsigned short* __restrict__ wvb,
                                                   unsigned short* __restrict__ wfb) {
  int i = blockIdx.x * 256 + threadIdx.x;
  if (i < 128 * 512) {
    int row = i >> 9, col = i & 511;
    float v = (row < 64) ? wq[row * 512 + col] : wk[(row - 64) * 512 + col];
    wqk[i] = f2b(v);
  }
  wvb[i] = f2b(wv[i]);
  wfb[i] = f2b(wf[i]);
}

// ---------------- generic MFMA GEMM:  C[m,n] = sum_k A[m,k] * B'[n,k] ----------------

enum { EPI_BF16 = 0, EPI_F32 = 1 };

template<int EPI, bool SPLITK = false>
__global__ __launch_bounds__(256)
void gemm_bt(const unsigned short* __restrict__ A, size_t lda, size_t sA,
             const unsigned short* __restrict__ Bm, size_t ldb, size_t sB,
             void* __restrict__ Cv, size_t ldc, size_t sCbytes, int K) {
  const int bz = blockIdx.z;
  const int m0 = blockIdx.x * 128, n0 = blockIdx.y * 128;
  char* Cb;
  if (SPLITK) {
    int bidx = bz & 3, ch = bz >> 2;
    A  += (size_t)bidx * sA + (size_t)ch * (size_t)K;
    Bm += (size_t)bidx * sB + (size_t)ch * (size_t)K;
    Cb = (char*)Cv + (size_t)bidx * sCbytes + (size_t)ch * 4u * sCbytes;
  } else {
    A  += (size_t)bz * sA;
    Bm += (size_t)bz * sB;
    Cb = (char*)Cv + (size_t)bz * sCbytes;
  }
  __shared__ unsigned short lsA[128 * 32];
  __shared__ unsigned short lsB[128 * 32];
  const int tid = threadIdx.x, lane = tid & 63, w = tid >> 6;
  const int wm = (w >> 1) * 64, wn = (w & 1) * 64;
  const int fr = lane & 15, fk = (lane >> 4) * 8;
  f32x4 acc[4][4];
#pragma unroll
  for (int i = 0; i < 4; ++i)
#pragma unroll
    for (int j = 0; j < 4; ++j) acc[i][j] = (f32x4){0.f, 0.f, 0.f, 0.f};

  const int i0 = tid, i1 = tid + 256;
  for (int k0 = 0; k0 < K; k0 += 32) {
    async16(A  + (size_t)(m0 + (i0 >> 2)) * lda + k0 + (i0 & 3) * 8, (char*)lsA + i0 * 16);
    async16(A  + (size_t)(m0 + (i1 >> 2)) * lda + k0 + (i1 & 3) * 8, (char*)lsA + i1 * 16);
    async16(Bm + (size_t)(n0 + (i0 >> 2)) * ldb + k0 + (i0 & 3) * 8, (char*)lsB + i0 * 16);
    async16(Bm + (size_t)(n0 + (i1 >> 2)) * ldb + k0 + (i1 & 3) * 8, (char*)lsB + i1 * 16);
    __syncthreads();
    short8 af[4], bfr[4];
#pragma unroll
    for (int mi = 0; mi < 4; ++mi)
      af[mi] = *(const short8*)&lsA[(wm + mi * 16 + fr) * 32 + fk];
#pragma unroll
    for (int ni = 0; ni < 4; ++ni)
      bfr[ni] = *(const short8*)&lsB[(wn + ni * 16 + fr) * 32 + fk];
#pragma unroll
    for (int mi = 0; mi < 4; ++mi)
#pragma unroll
      for (int ni = 0; ni < 4; ++ni)
        acc[mi][ni] = __builtin_amdgcn_mfma_f32_16x16x32_bf16(af[mi], bfr[ni], acc[mi][ni], 0, 0, 0);
    __syncthreads();
  }
#pragma unroll
  for (int mi = 0; mi < 4; ++mi)
#pragma unroll
    for (int ni = 0; ni < 4; ++ni)
#pragma unroll
      for (int r = 0; r < 4; ++r) {
        int gr = m0 + wm + mi * 16 + (lane >> 4) * 4 + r;
        int gc = n0 + wn + ni * 16 + fr;
        float v = acc[mi][ni][r];
        if (EPI == EPI_BF16) ((unsigned short*)Cb)[(size_t)gr * ldc + gc] = f2b(v);
        else                 ((float*)Cb)[(size_t)gr * ldc + gc] = v;
      }
}

// ---------------- fused position attention ----------------
// per block: 128 Q-rows x 256 out-cols; K-tiles of 128 over m.
// E^T = mfma(K,Q) -> exp -> P (bf16, swizzled LDS) + running rowsum -> P@V^T
// epilogue: sT = bf16(gpa*acc/l + gca*caT + 2x)
#define QR 128
#define CC 256
#define KT 128

__global__ __launch_bounds__(512, 2)
void fused_pa_k(const unsigned short* __restrict__ qkT,   // [B][N][128] (q|k)
                const unsigned short* __restrict__ vmat,  // [B][C][N]
                const unsigned short* __restrict__ caT,   // [B][N][C]
                const unsigned short* __restrict__ xnc,   // [B][N][C]
                const float* __restrict__ gpa_p, const float* __restrict__ gca_p,
                unsigned short* __restrict__ sT) {        // [B][N][C]
  __shared__ unsigned short lsQ[QR * 64];
  __shared__ unsigned short lsK[2][KT * 64];
  __shared__ unsigned short lsV[CC * KT];
  __shared__ unsigned short lsP[QR * KT];
  __shared__ float lsL[8][QR];
  __shared__ float invL[QR];

  const int bid = blockIdx.x;
  const int combo = bid & 7;                 // b*2+chalf -> same XCD shares V-half
  const int b = combo >> 1, chalf = combo & 1;
  const int qt = bid >> 3;
  const int n0 = qt * QR, c0 = chalf * CC;

  const int tid = threadIdx.x, lane = tid & 63, w = tid >> 6;
  const int fr = lane & 15, fq = lane >> 4;  // fragment row / k-quarter
  const int wr = w >> 2, wc = w & 3;         // wave out-tile 64x64

  const unsigned short* qk_b = qkT + (size_t)b * N_ * 128;
  const unsigned short* v_b  = vmat + (size_t)b * C_ * N_;

  f32x4 acc[4][4];
#pragma unroll
  for (int i = 0; i < 4; ++i)
#pragma unroll
    for (int j = 0; j < 4; ++j) acc[i][j] = (f32x4){0.f, 0.f, 0.f, 0.f};
  float lsum[8];
#pragma unroll
  for (int f = 0; f < 8; ++f) lsum[f] = 0.f;

  // stage Q (once) and K[0]
#pragma unroll
  for (int j = 0; j < 2; ++j) {
    int idx = j * 512 + tid;
    int r = idx >> 3, g = idx & 7;
    async16(qk_b + (size_t)(n0 + r) * 128 + ((g ^ (r & 7)) << 3), (char*)lsQ + idx * 16);
  }
#pragma unroll
  for (int j = 0; j < 2; ++j) {
    int idx = j * 512 + tid;
    int r = idx >> 3, g = idx & 7;
    async16(qk_b + (size_t)r * 128 + 64 + ((g ^ (r & 7)) << 3), (char*)lsK[0] + idx * 16);
  }
  __syncthreads();

  for (int it = 0; it < N_ / KT; ++it) {
    const int m0 = it * KT;
    // stage V[it]
#pragma unroll
    for (int j = 0; j < 8; ++j) {
      int idx = j * 512 + tid;
      int c = idx >> 4, g = idx & 15;
      async16(v_b + (size_t)(c0 + c) * N_ + m0 + ((g ^ (c & 7)) << 3), (char*)lsV + idx * 16);
    }
    // stage K[it+1]
    if (it < N_ / KT - 1) {
      unsigned short* dst = lsK[(it + 1) & 1];
#pragma unroll
      for (int j = 0; j < 2; ++j) {
        int idx = j * 512 + tid;
        int r = idx >> 3, g = idx & 7;
        async16(qk_b + (size_t)(m0 + KT + r) * 128 + 64 + ((g ^ (r & 7)) << 3),
                (char*)dst + idx * 16);
      }
    }
    // E^T = K . Q^T over k=64; wave w owns m-slice [w*16, w*16+16)
    const unsigned short* lk = lsK[it & 1];
    const int ms = w * 16;
    short8 afk[2];
#pragma unroll
    for (int kk = 0; kk < 2; ++kk)
      afk[kk] = *(const short8*)&lk[(ms + fr) * 64 + (((kk * 4 + fq) ^ (fr & 7)) << 3)];
#pragma unroll
    for (int f = 0; f < 8; ++f) {
      f32x4 e = (f32x4){0.f, 0.f, 0.f, 0.f};
#pragma unroll
      for (int kk = 0; kk < 2; ++kk) {
        short8 bq = *(const short8*)&lsQ[(f * 16 + fr) * 64 + (((kk * 4 + fq) ^ (fr & 7)) << 3)];
        e = __builtin_amdgcn_mfma_f32_16x16x32_bf16(afk[kk], bq, e, 0, 0, 0);
      }
      float p0 = __expf(e[0]), p1 = __expf(e[1]), p2 = __expf(e[2]), p3 = __expf(e[3]);
      float part = (p0 + p1) + (p2 + p3);
      part += __shfl_xor(part, 16, 64);
      part += __shfl_xor(part, 32, 64);
      lsum[f] += part;
      int n = f * 16 + fr;                     // P row
      int mb = ms + fq * 4;                    // 4 consecutive m
      us4_t pk = { f2b(p0), f2b(p1), f2b(p2), f2b(p3) };
      *(us4_t*)((char*)lsP + n * 256 + ((((mb >> 3) ^ (n & 7)) << 3) + (mb & 7)) * 2) = pk;
    }
    __syncthreads();   // P visible; V (and next K) landed
    // PV: out[n][c] += P[n][m] * V[c][m]
#pragma unroll
    for (int kk4 = 0; kk4 < 4; ++kk4) {
      short8 pa[4], vbf[4];
#pragma unroll
      for (int mi = 0; mi < 4; ++mi) {
        int n = wr * 64 + mi * 16 + fr;
        // byte-consistent with the P write: row stride 256 B, granule stride 16 B
        pa[mi] = *(const short8*)((const char*)lsP + n * 256 + (((kk4 * 4 + fq) ^ (n & 7)) << 4));
      }
#pragma unroll
      for (int ni = 0; ni < 4; ++ni) {
        int c = wc * 64 + ni * 16 + fr;
        // byte-consistent with the V stage: row stride 256 B, granule stride 16 B
        vbf[ni] = *(const short8*)((const char*)lsV + c * 256 + (((kk4 * 4 + fq) ^ (c & 7)) << 4));
      }
#pragma unroll
      for (int mi = 0; mi < 4; ++mi)
#pragma unroll
        for (int ni = 0; ni < 4; ++ni)
          acc[mi][ni] = __builtin_amdgcn_mfma_f32_16x16x32_bf16(pa[mi], vbf[ni], acc[mi][ni], 0, 0, 0);
    }
    __syncthreads();   // all reads of lsP/lsV done before next stage/overwrite
  }

  // reduce rowsums across waves -> 1/l
  if (lane < 16) {
#pragma unroll
    for (int f = 0; f < 8; ++f) lsL[w][f * 16 + lane] = lsum[f];
  }
  __syncthreads();
  if (tid < QR) {
    float s = 0.f;
#pragma unroll
    for (int ww = 0; ww < 8; ++ww) s += lsL[ww][tid];
    invL[tid] = 1.f / s;
  }
  __syncthreads();

  const float gpa = gpa_p[0], gca = gca_p[0];
#pragma unroll
  for (int mi = 0; mi < 4; ++mi)
#pragma unroll
    for (int ni = 0; ni < 4; ++ni)
#pragma unroll
      for (int r = 0; r < 4; ++r) {
        int nl = wr * 64 + mi * 16 + fq * 4 + r;
        int gn = n0 + nl;
        int gc = c0 + wc * 64 + ni * 16 + fr;
        size_t eo = ((size_t)b * N_ + gn) * C_ + gc;
        float sv = gpa * acc[mi][ni][r] * invL[nl] + gca * b2f(caT[eo]) + 2.f * b2f(xnc[eo]);
        sT[eo] = f2b(sv);
      }
}

// ---------------- channel-attention softmax over ce partials ----------------
__global__ __launch_bounds__(256) void ce_softmax_k(const float* __restrict__ cepart,
                                                    unsigned short* __restrict__ cattn) {
  int wid = threadIdx.x >> 6, lane = threadIdx.x & 63;
  size_t row = (size_t)blockIdx.x * 4 + wid;
  float v[8]; float mn = 3.4e38f;
#pragma unroll
  for (int i = 0; i < 8; ++i) {
    size_t idx = row * C_ + (size_t)(i * 64 + lane);
    float t = cepart[idx] + cepart[idx + 1048576] + cepart[idx + 2097152] + cepart[idx + 3145728];
    v[i] = t; mn = fminf(mn, t);
  }
#pragma unroll
  for (int o = 1; o < 64; o <<= 1) mn = fminf(mn, __shfl_xor(mn, o, 64));
  float s = 0.f, p[8];
#pragma unroll
  for (int i = 0; i < 8; ++i) { p[i] = expf(mn - v[i]); s += p[i]; }
#pragma unroll
  for (int o = 1; o < 64; o <<= 1) s += __shfl_xor(s, o, 64);
  float inv = 1.f / s;
  unsigned short* orow = cattn + row * C_;
#pragma unroll
  for (int i = 0; i < 8; ++i) orow[i * 64 + lane] = f2b(p[i] * inv);
}

// ---------------- BN statistics (two stage, deterministic) ----------------
__global__ __launch_bounds__(256) void bn_part_k(const float* __restrict__ yT,
                                                 float* __restrict__ part) {
  int p = blockIdx.x, t = threadIdx.x;
  const float* base = yT + (size_t)p * 256 * C_;
  float s0 = 0, q0 = 0, s1 = 0, q1 = 0;
  for (int r = 0; r < 256; ++r) {
    float a = base[(size_t)r * C_ + t];
    float b = base[(size_t)r * C_ + t + 256];
    s0 += a; q0 += a * a; s1 += b; q1 += b * b;
  }
  float* pp = part + (size_t)p * 1024;
  pp[t] = s0; pp[t + 256] = s1; pp[t + 512] = q0; pp[t + 768] = q1;
}

__global__ __launch_bounds__(256) void bn_final_k(const float* __restrict__ part,
                                                  const float* __restrict__ bns,
                                                  const float* __restrict__ bnb,
                                                  float* __restrict__ ab) {
  int t = threadIdx.x;
#pragma unroll
  for (int cc = 0; cc < 2; ++cc) {
    int c = t + cc * 256;
    float s = 0, q = 0;
    for (int p = 0; p < 64; ++p) { s += part[p * 1024 + c]; q += part[p * 1024 + 512 + c]; }
    float mean = s * (1.f / 16384.f);
    float var  = q * (1.f / 16384.f) - mean * mean;
    float istd = rsqrtf(var + BN_EPS);
    float a = bns[c] * istd;
    float b = bnb[c] - mean * a;
    ab[c * 2] = a; ab[c * 2 + 1] = b;
  }
}

__global__ __launch_bounds__(256) void bn_apply_k(const float* __restrict__ yT,
                                                  const float* __restrict__ ab,
                                                  float* __restrict__ out) {
  __shared__ float tile[64][65];
  int n0 = blockIdx.x * 64, o0 = blockIdx.y * 64, b = blockIdx.z;
  const float* yb = yT + ((size_t)b * N_ + n0) * C_ + o0;
#pragma unroll
  for (int j = 0; j < 16; ++j) {
    int lin = j * 256 + threadIdx.x;
    int rr = lin >> 6, cc = lin & 63;
    float v = yb[(size_t)rr * C_ + cc];
    float a = ab[(o0 + cc) * 2], bb = ab[(o0 + cc) * 2 + 1];
    tile[cc][rr] = fmaxf(v * a + bb, 0.f);
  }
  __syncthreads();
  float* ob = out + ((size_t)b * C_ + o0) * N_ + n0;
#pragma unroll
  for (int j = 0; j < 16; ++j) {
    int lin = j * 256 + threadIdx.x;
    int rr = lin >> 6, cc = lin & 63;
    ob[(size_t)rr * N_ + cc] = tile[rr][cc];
  }
}

// ---------------- host launch ----------------

extern "C" void kernel_launch(void* const* d_in, const int* in_sizes, int n_in,
                              void* d_out, int out_size, void* d_ws, size_t ws_size,
                              hipStream_t stream) {
  (void)in_sizes; (void)n_in; (void)out_size; (void)ws_size;
  const float* x   = (const float*)d_in[0];
  const float* wq  = (const float*)d_in[1];
  const float* wk  = (const float*)d_in[2];
  const float* wv  = (const float*)d_in[3];
  const float* wf  = (const float*)d_in[4];
  const float* gpa = (const float*)d_in[5];
  const float* gca = (const float*)d_in[6];
  const float* bns = (const float*)d_in[7];
  const float* bnb = (const float*)d_in[8];
  float* out = (float*)d_out;

  char* ws = (char*)d_ws;
  size_t off = 0;
  auto carve = [&](size_t bytes) -> char* {
    off = (off + 255) & ~(size_t)255;
    char* p = ws + off; off += bytes; return p;
  };

  unsigned short* xcn   = (unsigned short*)carve((size_t)B_ * C_ * N_ * 2);  // reused as sT
  unsigned short* xnc   = (unsigned short*)carve((size_t)B_ * C_ * N_ * 2);
  unsigned short* wqkb  = (unsigned short*)carve(128 * 512 * 2);
  unsigned short* wvb   = (unsigned short*)carve(512 * 512 * 2);
  unsigned short* wfb   = (unsigned short*)carve(512 * 512 * 2);
  unsigned short* qkT   = (unsigned short*)carve((size_t)B_ * N_ * 128 * 2);
  unsigned short* vmat  = (unsigned short*)carve((size_t)B_ * C_ * N_ * 2);
  float*          cepart= (float*)carve((size_t)4 * B_ * 512 * 512 * 4);     // reused as yT
  unsigned short* cattn = (unsigned short*)carve((size_t)B_ * 512 * 512 * 2);
  unsigned short* caT   = (unsigned short*)carve((size_t)B_ * N_ * C_ * 2);
  float*          bnpart= (float*)carve((size_t)64 * 1024 * 4);
  float*          abv   = (float*)carve(512 * 2 * 4);

  float* yT = cepart;                 // overlay: cepart dead after ce_softmax
  unsigned short* sT = xcn;           // overlay: xcn dead after ce GEMM

  // 1) conversions
  convert_x_k<<<dim3(C_ / 64, N_ / 64, B_), 256, 0, stream>>>(x, xcn, xnc);
  convert_w_k<<<dim3(1024), 256, 0, stream>>>(wq, wk, wv, wf, wqkb, wvb, wfb);

  // 2) qkT[n][0:128] = xnc @ wqk^T
  gemm_bt<EPI_BF16><<<dim3(32, 1, 4), 256, 0, stream>>>(
      xnc, 512, (size_t)N_ * C_, wqkb, 512, 0,
      qkT, 128, (size_t)N_ * 128 * 2, 512);

  // 3) v[c][m] = wv @ x
  gemm_bt<EPI_BF16><<<dim3(4, 32, 4), 256, 0, stream>>>(
      wvb, 512, 0, xnc, 512, (size_t)N_ * C_,
      vmat, N_, (size_t)C_ * N_ * 2, 512);

  // 4) ce partials = X X^T (split-K x4)
  gemm_bt<EPI_F32, true><<<dim3(4, 4, 16), 256, 0, stream>>>(
      xcn, N_, (size_t)C_ * N_, xcn, N_, (size_t)C_ * N_,
      cepart, 512, (size_t)512 * 512 * 4, 1024);

  // 5) channel softmax -> cattn bf16
  ce_softmax_k<<<dim3(B_ * 512 / 4), 256, 0, stream>>>(cepart, cattn);

  // 6) caT[n][c] = xnc @ cattn^T
  gemm_bt<EPI_BF16><<<dim3(32, 4, 4), 256, 0, stream>>>(
      xnc, 512, (size_t)N_ * C_, cattn, 512, (size_t)512 * 512,
      caT, 512, (size_t)N_ * C_ * 2, 512);

  // 7) fused position attention + combine epilogue -> sT
  fused_pa_k<<<dim3(256), 512, 0, stream>>>(qkT, vmat, caT, xnc, gpa, gca, sT);

  // 8) yT[n][o] = sT @ wfuse^T (fp32)
  gemm_bt<EPI_F32><<<dim3(32, 4, 4), 256, 0, stream>>>(
      sT, 512, (size_t)N_ * C_, wfb, 512, 0,
      yT, 512, (size_t)N_ * C_ * 4, 512);

  // 9) BN stats + apply + transpose + relu
  bn_part_k<<<dim3(64), 256, 0, stream>>>(yT, bnpart);
  bn_final_k<<<dim3(1), 256, 0, stream>>>(bnpart, bns, bnb, abv);
  bn_apply_k<<<dim3(N_ / 64, C_ / 64, B_), 256, 0, stream>>>(yT, abv, out);
}